// Round 2
// baseline (500.187 us; speedup 1.0000x reference)
//
#include <hip/hip_runtime.h>

typedef __bf16 bf16x8 __attribute__((ext_vector_type(8)));
typedef float floatx4 __attribute__((ext_vector_type(4)));

static constexpr int ROW_IN  = 160;   // 64 scalars + 32*3 vectors
static constexpr int ROW_OUT = 160;   // 64 + 32*3
static constexpr int LDS_STRIDE = 164; // +4 pad breaks the 160%32==0 bank aliasing

// constants (C_SV1*INV_SQRT3 == sqrt(1/128) == C_SS0; C_VS1*INV_SQRT3 == 1/8)
static constexpr float C_SS0_F    = 0.08838834764831845f; // sqrt(1/128)
static constexpr float C_VV0_I3_F = 0.07216878364870323f; // sqrt(1/64)/sqrt(3)
static constexpr float C_SV1_I3_F = 0.08838834764831845f; // sqrt(3/128)/sqrt(3)
static constexpr float C_VS1_I3_F = 0.125f;               // sqrt(3/64)/sqrt(3)

__device__ __forceinline__ floatx4 mfma16(bf16x8 a, bf16x8 b, floatx4 c) {
    return __builtin_amdgcn_mfma_f32_16x16x32_bf16(a, b, c, 0, 0, 0);
}

// Weights=A, x-rows=B (identical lane->data maps for A and B fragments), so
// D[row=quad*4+r][col=lane&15] has row = output FEATURE, col = BATCH row.
// -> epilogue x2 factors are lane-local, stores are direct aligned float4.
// Input path: coalesced 1KB-per-instruction global loads (prefetched one tile
// ahead) staged through a wave-private LDS buffer; no barriers, lgkmcnt only.
__global__ __launch_bounds__(256, 2)
void o3tp_kernel(const float* __restrict__ x1, const float* __restrict__ x2,
                 const float* __restrict__ Wss0, const float* __restrict__ Wvv0,
                 const float* __restrict__ Wsv1, const float* __restrict__ Wvs1,
                 const float* __restrict__ bias0, float* __restrict__ out, int n)
{
    // wave-private staging buffer: 16 rows x 164 floats (10496 B/wave, 42 KB/block)
    __shared__ float lds[4][16 * LDS_STRIDE];
    float* __restrict__ tl = lds[threadIdx.x >> 6];

    const int lane = threadIdx.x & 63;
    const int m = lane & 15;           // batch row within 16-tile (B-frag n / D col)
    const int q = lane >> 4;           // quad: k-slice (A/B) or feature-subrow group (D)

    // ---------- weight fragments (A-operands), built once per wave ----------
    bf16x8 Wss[2][4];   // Wss0 (K=64 -> 2 k-tiles) x (64 feats -> 4 tiles)
    bf16x8 Wvv[4];      // Wvv0 (K=32) x 4 feat-tiles
    bf16x8 Wsv[2][2];   // Wsv1 (K=64) x 2 feat-tiles, scaled by C_SV1/sqrt3
    bf16x8 Wvs[2];      // Wvs1 (K=32) x 2 feat-tiles (scale folded into B)
#pragma unroll
    for (int kt = 0; kt < 2; ++kt)
#pragma unroll
        for (int ct = 0; ct < 4; ++ct)
#pragma unroll
            for (int j = 0; j < 8; ++j)
                Wss[kt][ct][j] = (__bf16)Wss0[(kt*32 + q*8 + j)*64 + ct*16 + m];
#pragma unroll
    for (int ct = 0; ct < 4; ++ct)
#pragma unroll
        for (int j = 0; j < 8; ++j)
            Wvv[ct][j] = (__bf16)Wvv0[(q*8 + j)*64 + ct*16 + m];
#pragma unroll
    for (int kt = 0; kt < 2; ++kt)
#pragma unroll
        for (int ct = 0; ct < 2; ++ct)
#pragma unroll
            for (int j = 0; j < 8; ++j)
                Wsv[kt][ct][j] = (__bf16)(Wsv1[(kt*32 + q*8 + j)*32 + ct*16 + m] * C_SV1_I3_F);
#pragma unroll
    for (int ct = 0; ct < 2; ++ct)
#pragma unroll
        for (int j = 0; j < 8; ++j)
            Wvs[ct][j] = (__bf16)Wvs1[(q*8 + j)*32 + ct*16 + m];

    // bias for features w = ct*16 + q*4 + r, used directly as MFMA C-in
    floatx4 bias_c[4];
#pragma unroll
    for (int ct = 0; ct < 4; ++ct)
        bias_c[ct] = *(const floatx4*)(bias0 + ct*16 + q*4);

    const floatx4 zero = {0.f, 0.f, 0.f, 0.f};

    const int n_tiles = n >> 4;  // 400000/16 = 25000
    const int wid     = blockIdx.x * (blockDim.x >> 6) + (threadIdx.x >> 6);
    const int n_waves = gridDim.x * (blockDim.x >> 6);

    // prefetch registers (live across MFMA stage; written to LDS post-epilogue)
    float4 v[10];
    float4 rx2;

    auto GLOAD = [&](int t) {   // coalesced: 10 x 1KB contiguous chunks
        const float* __restrict__ src = x1 + (size_t)(t << 4) * ROW_IN;
#pragma unroll
        for (int it = 0; it < 10; ++it)
            v[it] = *(const float4*)(src + (it*64 + lane)*4);
        rx2 = *(const float4*)(x2 + (size_t)((t << 4) + m) * 4);
    };
    auto LDSWRITE = [&]() {
#pragma unroll
        for (int it = 0; it < 10; ++it) {
            const int f   = it*64 + lane;
            const int row = f / 40;              // 40 float4 per 160-float row
            const int col = f*4 - row*ROW_IN;
            *(float4*)(tl + row*LDS_STRIDE + col) = v[it];
        }
    };

    int tile = wid;
    if (tile >= n_tiles) return;

    // prologue: stage first tile
    GLOAD(tile);
    LDSWRITE();
    asm volatile("s_waitcnt lgkmcnt(0)" ::: "memory");   // cross-lane LDS visibility

    for (; tile < n_tiles; ) {
        // x2 of the CURRENT tile (rx2 is overwritten by the prefetch below)
        const float sx = rx2.x, xy = rx2.y, xz = rx2.z, xw = rx2.w;
        const int row0 = tile << 4;

        // ---- issue next tile's global loads first: latency hides under
        //      LDS reads + fragment build + MFMA + epilogue stores ----
        tile += n_waves;
        const bool have_next = (tile < n_tiles);
        if (have_next) GLOAD(tile);

        // ---- A-frag raw data from LDS (current tile), lane reads its row m ----
        const float* __restrict__ xr = tl + m * LDS_STRIDE;
        float4 s0 = *(const float4*)(xr + q*8);
        float4 s1 = *(const float4*)(xr + q*8 + 4);
        float4 s2 = *(const float4*)(xr + 32 + q*8);
        float4 s3 = *(const float4*)(xr + 32 + q*8 + 4);
        float4 cc[6];
#pragma unroll
        for (int t = 0; t < 6; ++t)
            cc[t] = *(const float4*)(xr + 64 + q*24 + t*4);

        // ---- fragment build (numerics identical to verified kernel) ----
        bf16x8 a_s[2], a_ss[2];
        const float sscale = sx * C_SS0_F;
        {
            const float vv0[8] = {s0.x, s0.y, s0.z, s0.w, s1.x, s1.y, s1.z, s1.w};
            const float vv1[8] = {s2.x, s2.y, s2.z, s2.w, s3.x, s3.y, s3.z, s3.w};
#pragma unroll
            for (int j = 0; j < 8; ++j) {
                a_s[0][j]  = (__bf16)vv0[j];
                a_ss[0][j] = (__bf16)(vv0[j] * sscale);
                a_s[1][j]  = (__bf16)vv1[j];
                a_ss[1][j] = (__bf16)(vv1[j] * sscale);
            }
        }
        float c[24];
#pragma unroll
        for (int t = 0; t < 6; ++t) {
            c[t*4+0] = cc[t].x; c[t*4+1] = cc[t].y; c[t*4+2] = cc[t].z; c[t*4+3] = cc[t].w;
        }
        bf16x8 a_d, a_v0, a_v1, a_v2;
        const float gscale = sx * C_VS1_I3_F;
#pragma unroll
        for (int j = 0; j < 8; ++j) {
            const float d = (c[3*j+0]*xy + c[3*j+1]*xz + c[3*j+2]*xw) * C_VV0_I3_F;
            a_d[j]  = (__bf16)d;
            a_v0[j] = (__bf16)(c[3*j+0] * gscale);
            a_v1[j] = (__bf16)(c[3*j+1] * gscale);
            a_v2[j] = (__bf16)(c[3*j+2] * gscale);
        }

        // ---- MFMAs (22, all K useful); bias folded into C-in of acc0 ----
        floatx4 acc0[4], accT[2], accG0[2], accG1[2], accG2[2];
#pragma unroll
        for (int ct = 0; ct < 4; ++ct) {
            acc0[ct] = mfma16(Wss[0][ct], a_ss[0], bias_c[ct]);
            acc0[ct] = mfma16(Wss[1][ct], a_ss[1], acc0[ct]);
            acc0[ct] = mfma16(Wvv[ct],    a_d,     acc0[ct]);
        }
#pragma unroll
        for (int ct = 0; ct < 2; ++ct) {
            accT[ct]  = mfma16(Wsv[0][ct], a_s[0], zero);
            accT[ct]  = mfma16(Wsv[1][ct], a_s[1], accT[ct]);
            accG0[ct] = mfma16(Wvs[ct], a_v0, zero);
            accG1[ct] = mfma16(Wvs[ct], a_v1, zero);
            accG2[ct] = mfma16(Wvs[ct], a_v2, zero);
        }

        // ---- epilogue: direct coalesced float4 stores (no LDS, no shfl) ----
        // lane owns batch row (row0+m), features w = ct*16 + q*4 + r
        float* __restrict__ dst = out + (size_t)(row0 + m) * ROW_OUT;
#pragma unroll
        for (int ct = 0; ct < 4; ++ct)
            *(floatx4*)(dst + ct*16 + q*4) = acc0[ct];
#pragma unroll
        for (int ct = 0; ct < 2; ++ct) {
            float vals[12];   // features 64 + 48*ct + 12*q + (3r+i), 12 consecutive floats
#pragma unroll
            for (int r = 0; r < 4; ++r) {
                const float t = accT[ct][r];
                vals[3*r+0] = fmaf(xy, t, accG0[ct][r]);
                vals[3*r+1] = fmaf(xz, t, accG1[ct][r]);
                vals[3*r+2] = fmaf(xw, t, accG2[ct][r]);
            }
            float* __restrict__ p = dst + 64 + 48*ct + 12*q;
#pragma unroll
            for (int s = 0; s < 3; ++s) {
                floatx4 o = {vals[4*s+0], vals[4*s+1], vals[4*s+2], vals[4*s+3]};
                *(floatx4*)(p + 4*s) = o;
            }
        }

        // ---- stage next tile into LDS (loads have had MFMA+epilogue to land) ----
        if (have_next) {
            asm volatile("" ::: "memory");   // keep ds_writes after this point
            LDSWRITE();
            asm volatile("s_waitcnt lgkmcnt(0)" ::: "memory");
        }
    }
}

extern "C" void kernel_launch(void* const* d_in, const int* in_sizes, int n_in,
                              void* d_out, int out_size, void* d_ws, size_t ws_size,
                              hipStream_t stream) {
    const float* x1    = (const float*)d_in[0];
    const float* x2    = (const float*)d_in[1];
    const float* Wss0  = (const float*)d_in[2];
    const float* Wvv0  = (const float*)d_in[3];
    const float* Wsv1  = (const float*)d_in[4];
    const float* Wvs1  = (const float*)d_in[5];
    const float* bias0 = (const float*)d_in[6];
    float* out = (float*)d_out;
    const int n = in_sizes[0] / ROW_IN;   // 400000

    // 512 blocks x 4 waves = 2048 waves (8/CU at 2 blocks/CU); ~12 tiles/wave
    // amortizes the one-time weight-fragment build.
    dim3 grid(512), block(256);
    hipLaunchKernelGGL(o3tp_kernel, grid, block, 0, stream,
                       x1, x2, Wss0, Wvv0, Wsv1, Wvs1, bias0, out, n);
}

// Round 3
// 479.236 us; speedup vs baseline: 1.0437x; 1.0437x over previous
//
#include <hip/hip_runtime.h>

typedef __bf16 bf16x8 __attribute__((ext_vector_type(8)));
typedef float floatx4 __attribute__((ext_vector_type(4)));

static constexpr int ROW_IN  = 160;   // 64 scalars + 32*3 vectors
static constexpr int ROW_OUT = 160;   // 64 + 32*3

// constants (C_SV1*INV_SQRT3 == sqrt(1/128) == C_SS0; C_VS1*INV_SQRT3 == 1/8)
static constexpr float C_SS0_F    = 0.08838834764831845f; // sqrt(1/128)
static constexpr float C_VV0_I3_F = 0.07216878364870323f; // sqrt(1/64)/sqrt(3)
static constexpr float C_SV1_I3_F = 0.08838834764831845f; // sqrt(3/128)/sqrt(3)
static constexpr float C_VS1_I3_F = 0.125f;               // sqrt(3/64)/sqrt(3)

__device__ __forceinline__ floatx4 mfma16(bf16x8 a, bf16x8 b, floatx4 c) {
    return __builtin_amdgcn_mfma_f32_16x16x32_bf16(a, b, c, 0, 0, 0);
}

// Weights=A, x-rows=B (identical lane->data maps for A and B fragments), so
// D[row=quad*4+r][col=lane&15] has row = output FEATURE, col = BATCH row.
// Input path: per-lane register loads (no LDS staging -- R2 showed staging
// costs ~60us in lgkm drains; read fragmentation is healed by L2).
// Output path: out0 dense direct; out1 repacked via a tiny wave-private LDS
// buffer so every store instruction covers full 64B lines per row (kills the
// ~2x WRITE_SIZE inflation seen in R2's counters).
__global__ __launch_bounds__(256, 3)
void o3tp_kernel(const float* __restrict__ x1, const float* __restrict__ x2,
                 const float* __restrict__ Wss0, const float* __restrict__ Wvv0,
                 const float* __restrict__ Wsv1, const float* __restrict__ Wvs1,
                 const float* __restrict__ bias0, float* __restrict__ out, int n)
{
    // out1 repack buffer: 16 rows x 96 floats per wave (6144 B/wave, 24.6 KB/block)
    __shared__ float lds[4][16 * 96];
    float* __restrict__ tl = lds[threadIdx.x >> 6];

    const int lane = threadIdx.x & 63;
    const int m = lane & 15;           // batch row within 16-tile (B-frag n / D col)
    const int q = lane >> 4;           // quad: k-slice (A/B) or feature-subrow group (D)
    const int swz = (m & 7) << 2;      // XOR swizzle for LDS dword columns

    // ---------- weight fragments (A-operands), built once per wave ----------
    bf16x8 Wss[2][4];   // Wss0 (K=64 -> 2 k-tiles) x (64 feats -> 4 tiles)
    bf16x8 Wvv[4];      // Wvv0 (K=32) x 4 feat-tiles
    bf16x8 Wsv[2][2];   // Wsv1 (K=64) x 2 feat-tiles, scaled by C_SV1/sqrt3
    bf16x8 Wvs[2];      // Wvs1 (K=32) x 2 feat-tiles (scale folded into B)
#pragma unroll
    for (int kt = 0; kt < 2; ++kt)
#pragma unroll
        for (int ct = 0; ct < 4; ++ct)
#pragma unroll
            for (int j = 0; j < 8; ++j)
                Wss[kt][ct][j] = (__bf16)Wss0[(kt*32 + q*8 + j)*64 + ct*16 + m];
#pragma unroll
    for (int ct = 0; ct < 4; ++ct)
#pragma unroll
        for (int j = 0; j < 8; ++j)
            Wvv[ct][j] = (__bf16)Wvv0[(q*8 + j)*64 + ct*16 + m];
#pragma unroll
    for (int kt = 0; kt < 2; ++kt)
#pragma unroll
        for (int ct = 0; ct < 2; ++ct)
#pragma unroll
            for (int j = 0; j < 8; ++j)
                Wsv[kt][ct][j] = (__bf16)(Wsv1[(kt*32 + q*8 + j)*32 + ct*16 + m] * C_SV1_I3_F);
#pragma unroll
    for (int ct = 0; ct < 2; ++ct)
#pragma unroll
        for (int j = 0; j < 8; ++j)
            Wvs[ct][j] = (__bf16)Wvs1[(q*8 + j)*32 + ct*16 + m];

    // bias for features w = ct*16 + q*4 + r, used directly as MFMA C-in
    floatx4 bias_c[4];
#pragma unroll
    for (int ct = 0; ct < 4; ++ct)
        bias_c[ct] = *(const floatx4*)(bias0 + ct*16 + q*4);

    const floatx4 zero = {0.f, 0.f, 0.f, 0.f};

    const int n_tiles = n >> 4;  // 400000/16 = 25000
    const int wid     = blockIdx.x * (blockDim.x >> 6) + (threadIdx.x >> 6);
    const int n_waves = gridDim.x * (blockDim.x >> 6);

    // ---- raw per-lane tile data (prefetched one tile ahead, pure registers) ----
    float4 rs[4];   // row m scalars: floats [kt*32+q*8 .. +8)
    float4 rc[6];   // row m vector part: floats [64+q*24 .. +24)
    float4 rx2;     // x2 row m

    auto LOAD = [&](int tile) {
        const float* __restrict__ src = x1 + (size_t)(tile*16 + m) * ROW_IN;
        rs[0] = *(const float4*)(src + q*8);
        rs[1] = *(const float4*)(src + q*8 + 4);
        rs[2] = *(const float4*)(src + 32 + q*8);
        rs[3] = *(const float4*)(src + 32 + q*8 + 4);
#pragma unroll
        for (int t = 0; t < 6; ++t)
            rc[t] = *(const float4*)(src + 64 + q*24 + t*4);
        rx2 = *(const float4*)(x2 + (size_t)(tile*16 + m) * 4);
    };

    int tile = wid;
    if (tile < n_tiles) LOAD(tile);

    for (; tile < n_tiles; ) {
        // ---- stage 1: raw regs -> fragments (numerics identical to verified kernel) ----
        bf16x8 a_s[2], a_ss[2];
        const float sscale = rx2.x * C_SS0_F;
#pragma unroll
        for (int kt = 0; kt < 2; ++kt) {
            const float vv[8] = {rs[2*kt].x, rs[2*kt].y, rs[2*kt].z, rs[2*kt].w,
                                 rs[2*kt+1].x, rs[2*kt+1].y, rs[2*kt+1].z, rs[2*kt+1].w};
#pragma unroll
            for (int j = 0; j < 8; ++j) {
                a_s[kt][j]  = (__bf16)vv[j];
                a_ss[kt][j] = (__bf16)(vv[j] * sscale);
            }
        }
        float c[24];
#pragma unroll
        for (int t = 0; t < 6; ++t) {
            c[t*4+0] = rc[t].x; c[t*4+1] = rc[t].y; c[t*4+2] = rc[t].z; c[t*4+3] = rc[t].w;
        }
        bf16x8 a_d, a_v0, a_v1, a_v2;
        const float gscale = rx2.x * C_VS1_I3_F;
        const float xy = rx2.y, xz = rx2.z, xw = rx2.w;   // rx2 overwritten by prefetch
#pragma unroll
        for (int j = 0; j < 8; ++j) {
            const float d = (c[3*j+0]*xy + c[3*j+1]*xz + c[3*j+2]*xw) * C_VV0_I3_F;
            a_d[j]  = (__bf16)d;
            a_v0[j] = (__bf16)(c[3*j+0] * gscale);
            a_v1[j] = (__bf16)(c[3*j+1] * gscale);
            a_v2[j] = (__bf16)(c[3*j+2] * gscale);
        }

        const int row0 = tile << 4;

        // ---- stage 2: prefetch next tile (latency hidden under MFMAs + epilogue) ----
        tile += n_waves;
        if (tile < n_tiles) LOAD(tile);

        // ---- stage 3: MFMAs (22, all K useful); bias folded into C-in of acc0 ----
        floatx4 acc0[4], accT[2], accG0[2], accG1[2], accG2[2];
#pragma unroll
        for (int ct = 0; ct < 4; ++ct) {
            acc0[ct] = mfma16(Wss[0][ct], a_ss[0], bias_c[ct]);
            acc0[ct] = mfma16(Wss[1][ct], a_ss[1], acc0[ct]);
            acc0[ct] = mfma16(Wvv[ct],    a_d,     acc0[ct]);
        }
#pragma unroll
        for (int ct = 0; ct < 2; ++ct) {
            accT[ct]  = mfma16(Wsv[0][ct], a_s[0], zero);
            accT[ct]  = mfma16(Wsv[1][ct], a_s[1], accT[ct]);
            accG0[ct] = mfma16(Wvs[ct], a_v0, zero);
            accG1[ct] = mfma16(Wvs[ct], a_v1, zero);
            accG2[ct] = mfma16(Wvs[ct], a_v2, zero);
        }

        // ---- stage 4a: out0, direct dense stores (per instr: 16 rows x 64B contiguous) ----
        float* __restrict__ dst = out + (size_t)(row0 + m) * ROW_OUT;
#pragma unroll
        for (int ct = 0; ct < 4; ++ct)
            *(floatx4*)(dst + ct*16 + q*4) = acc0[ct];

        // ---- stage 4b: out1 repack through LDS for dense 64B-per-row stores ----
        // lane (q,m) owns rel floats [48ct+12q .. +12) of row m's out1 region.
        asm volatile("" ::: "memory");
#pragma unroll
        for (int ct = 0; ct < 2; ++ct) {
            float vals[12];
#pragma unroll
            for (int r = 0; r < 4; ++r) {
                const float t = accT[ct][r];
                vals[3*r+0] = fmaf(xy, t, accG0[ct][r]);
                vals[3*r+1] = fmaf(xz, t, accG1[ct][r]);
                vals[3*r+2] = fmaf(xw, t, accG2[ct][r]);
            }
#pragma unroll
            for (int t = 0; t < 3; ++t) {
                const int cs = (48*ct + 12*q + 4*t) ^ swz;   // bijective within [0,96)
                floatx4 piece = {vals[4*t+0], vals[4*t+1], vals[4*t+2], vals[4*t+3]};
                *(floatx4*)(tl + m*96 + cs) = piece;
            }
        }
        asm volatile("s_waitcnt lgkmcnt(0)" ::: "memory");   // cross-lane visibility (wave-private)
        // dense stores: instr p writes rel floats [16p,16p+16) of all 16 rows (1KB/instr)
#pragma unroll
        for (int p = 0; p < 6; ++p) {
            const int cs = (16*p + 4*q) ^ swz;
            const floatx4 piece = *(const floatx4*)(tl + m*96 + cs);
            *(floatx4*)(dst + 64 + 16*p + 4*q) = piece;
        }
    }
}

extern "C" void kernel_launch(void* const* d_in, const int* in_sizes, int n_in,
                              void* d_out, int out_size, void* d_ws, size_t ws_size,
                              hipStream_t stream) {
    const float* x1    = (const float*)d_in[0];
    const float* x2    = (const float*)d_in[1];
    const float* Wss0  = (const float*)d_in[2];
    const float* Wvv0  = (const float*)d_in[3];
    const float* Wsv1  = (const float*)d_in[4];
    const float* Wvs1  = (const float*)d_in[5];
    const float* bias0 = (const float*)d_in[6];
    float* out = (float*)d_out;
    const int n = in_sizes[0] / ROW_IN;   // 400000

    // 768 blocks x 4 waves = 3072 waves -> 3 blocks/CU, 12 waves/CU (VGPR~92
    // allows 3/SIMD); ~8 tiles/wave amortizes the weight-fragment build.
    dim3 grid(768), block(256);
    hipLaunchKernelGGL(o3tp_kernel, grid, block, 0, stream,
                       x1, x2, Wss0, Wvv0, Wsv1, Wvs1, bias0, out, n);
}

// Round 4
// 472.644 us; speedup vs baseline: 1.0583x; 1.0139x over previous
//
#include <hip/hip_runtime.h>

typedef __bf16 bf16x8 __attribute__((ext_vector_type(8)));
typedef float floatx4 __attribute__((ext_vector_type(4)));

static constexpr int ROW_IN  = 160;   // 64 scalars + 32*3 vectors
static constexpr int ROW_OUT = 160;   // 64 + 32*3

// constants (C_SV1*INV_SQRT3 == sqrt(1/128) == C_SS0; C_VS1*INV_SQRT3 == 1/8)
static constexpr float C_SS0_F    = 0.08838834764831845f; // sqrt(1/128)
static constexpr float C_VV0_I3_F = 0.07216878364870323f; // sqrt(1/64)/sqrt(3)
static constexpr float C_SV1_I3_F = 0.08838834764831845f; // sqrt(3/128)/sqrt(3)
static constexpr float C_VS1_I3_F = 0.125f;               // sqrt(3/64)/sqrt(3)

__device__ __forceinline__ floatx4 mfma16(bf16x8 a, bf16x8 b, floatx4 c) {
    return __builtin_amdgcn_mfma_f32_16x16x32_bf16(a, b, c, 0, 0, 0);
}

// Weights=A, x-rows=B (identical lane->data maps for A and B fragments), so
// D[row=quad*4+r][col=lane&15] has row = output FEATURE, col = BATCH row.
// Input path: per-lane register loads, 1-tile prefetch (no LDS staging).
// Output path: out0 dense direct; out1 repacked via a tiny wave-private LDS
// buffer (keeps WRITE_SIZE at ~293MB, R3-verified). R4 change: the repack is
// fenced with sched_barrier(0) + a BARE lgkmcnt wait instead of full
// "memory"-clobber fences -- R3's per-tile compiler memory barriers
// compartmentalized the VMEM stream and capped BW at 3.3 TB/s.
__global__ __launch_bounds__(256, 3)
void o3tp_kernel(const float* __restrict__ x1, const float* __restrict__ x2,
                 const float* __restrict__ Wss0, const float* __restrict__ Wvv0,
                 const float* __restrict__ Wsv1, const float* __restrict__ Wvs1,
                 const float* __restrict__ bias0, float* __restrict__ out, int n)
{
    // out1 repack buffer: 16 rows x 96 floats per wave (6144 B/wave, 24.6 KB/block)
    __shared__ float lds[4][16 * 96];
    float* __restrict__ tl = lds[threadIdx.x >> 6];

    const int lane = threadIdx.x & 63;
    const int m = lane & 15;           // batch row within 16-tile (B-frag n / D col)
    const int q = lane >> 4;           // quad: k-slice (A/B) or feature-subrow group (D)
    const int swz = (m & 7) << 2;      // XOR swizzle for LDS dword columns

    // ---------- weight fragments (A-operands), built once per wave ----------
    bf16x8 Wss[2][4];   // Wss0 (K=64 -> 2 k-tiles) x (64 feats -> 4 tiles)
    bf16x8 Wvv[4];      // Wvv0 (K=32) x 4 feat-tiles
    bf16x8 Wsv[2][2];   // Wsv1 (K=64) x 2 feat-tiles, scaled by C_SV1/sqrt3
    bf16x8 Wvs[2];      // Wvs1 (K=32) x 2 feat-tiles (scale folded into B)
#pragma unroll
    for (int kt = 0; kt < 2; ++kt)
#pragma unroll
        for (int ct = 0; ct < 4; ++ct)
#pragma unroll
            for (int j = 0; j < 8; ++j)
                Wss[kt][ct][j] = (__bf16)Wss0[(kt*32 + q*8 + j)*64 + ct*16 + m];
#pragma unroll
    for (int ct = 0; ct < 4; ++ct)
#pragma unroll
        for (int j = 0; j < 8; ++j)
            Wvv[ct][j] = (__bf16)Wvv0[(q*8 + j)*64 + ct*16 + m];
#pragma unroll
    for (int kt = 0; kt < 2; ++kt)
#pragma unroll
        for (int ct = 0; ct < 2; ++ct)
#pragma unroll
            for (int j = 0; j < 8; ++j)
                Wsv[kt][ct][j] = (__bf16)(Wsv1[(kt*32 + q*8 + j)*32 + ct*16 + m] * C_SV1_I3_F);
#pragma unroll
    for (int ct = 0; ct < 2; ++ct)
#pragma unroll
        for (int j = 0; j < 8; ++j)
            Wvs[ct][j] = (__bf16)Wvs1[(q*8 + j)*32 + ct*16 + m];

    // bias for features w = ct*16 + q*4 + r, used directly as MFMA C-in
    floatx4 bias_c[4];
#pragma unroll
    for (int ct = 0; ct < 4; ++ct)
        bias_c[ct] = *(const floatx4*)(bias0 + ct*16 + q*4);

    const floatx4 zero = {0.f, 0.f, 0.f, 0.f};

    const int n_tiles = n >> 4;  // 400000/16 = 25000
    const int wid     = blockIdx.x * (blockDim.x >> 6) + (threadIdx.x >> 6);
    const int n_waves = gridDim.x * (blockDim.x >> 6);

    // ---- raw per-lane tile data (prefetched one tile ahead, pure registers) ----
    float4 rs[4];   // row m scalars: floats [kt*32+q*8 .. +8)
    float4 rc[6];   // row m vector part: floats [64+q*24 .. +24)
    float4 rx2;     // x2 row m

    auto LOAD = [&](int tile) {
        const float* __restrict__ src = x1 + (size_t)(tile*16 + m) * ROW_IN;
        rs[0] = *(const float4*)(src + q*8);
        rs[1] = *(const float4*)(src + q*8 + 4);
        rs[2] = *(const float4*)(src + 32 + q*8);
        rs[3] = *(const float4*)(src + 32 + q*8 + 4);
#pragma unroll
        for (int t = 0; t < 6; ++t)
            rc[t] = *(const float4*)(src + 64 + q*24 + t*4);
        rx2 = *(const float4*)(x2 + (size_t)(tile*16 + m) * 4);
    };

    int tile = wid;
    if (tile < n_tiles) LOAD(tile);

    for (; tile < n_tiles; ) {
        // ---- stage 1: raw regs -> fragments (numerics identical to verified kernel) ----
        bf16x8 a_s[2], a_ss[2];
        const float sscale = rx2.x * C_SS0_F;
#pragma unroll
        for (int kt = 0; kt < 2; ++kt) {
            const float vv[8] = {rs[2*kt].x, rs[2*kt].y, rs[2*kt].z, rs[2*kt].w,
                                 rs[2*kt+1].x, rs[2*kt+1].y, rs[2*kt+1].z, rs[2*kt+1].w};
#pragma unroll
            for (int j = 0; j < 8; ++j) {
                a_s[kt][j]  = (__bf16)vv[j];
                a_ss[kt][j] = (__bf16)(vv[j] * sscale);
            }
        }
        float c[24];
#pragma unroll
        for (int t = 0; t < 6; ++t) {
            c[t*4+0] = rc[t].x; c[t*4+1] = rc[t].y; c[t*4+2] = rc[t].z; c[t*4+3] = rc[t].w;
        }
        bf16x8 a_d, a_v0, a_v1, a_v2;
        const float gscale = rx2.x * C_VS1_I3_F;
        const float xy = rx2.y, xz = rx2.z, xw = rx2.w;   // rx2 overwritten by prefetch
#pragma unroll
        for (int j = 0; j < 8; ++j) {
            const float d = (c[3*j+0]*xy + c[3*j+1]*xz + c[3*j+2]*xw) * C_VV0_I3_F;
            a_d[j]  = (__bf16)d;
            a_v0[j] = (__bf16)(c[3*j+0] * gscale);
            a_v1[j] = (__bf16)(c[3*j+1] * gscale);
            a_v2[j] = (__bf16)(c[3*j+2] * gscale);
        }

        const int row0 = tile << 4;

        // ---- stage 2: prefetch next tile (latency hidden under MFMAs + epilogue) ----
        tile += n_waves;
        if (tile < n_tiles) LOAD(tile);

        // ---- stage 3: MFMAs (22, all K useful); bias folded into C-in of acc0 ----
        floatx4 acc0[4], accT[2], accG0[2], accG1[2], accG2[2];
#pragma unroll
        for (int ct = 0; ct < 4; ++ct) {
            acc0[ct] = mfma16(Wss[0][ct], a_ss[0], bias_c[ct]);
            acc0[ct] = mfma16(Wss[1][ct], a_ss[1], acc0[ct]);
            acc0[ct] = mfma16(Wvv[ct],    a_d,     acc0[ct]);
        }
#pragma unroll
        for (int ct = 0; ct < 2; ++ct) {
            accT[ct]  = mfma16(Wsv[0][ct], a_s[0], zero);
            accT[ct]  = mfma16(Wsv[1][ct], a_s[1], accT[ct]);
            accG0[ct] = mfma16(Wvs[ct], a_v0, zero);
            accG1[ct] = mfma16(Wvs[ct], a_v1, zero);
            accG2[ct] = mfma16(Wvs[ct], a_v2, zero);
        }

        // ---- stage 4a: out0, direct dense stores (per instr: 16 rows x 64B contiguous) ----
        float* __restrict__ dst = out + (size_t)(row0 + m) * ROW_OUT;
#pragma unroll
        for (int ct = 0; ct < 4; ++ct)
            *(floatx4*)(dst + ct*16 + q*4) = acc0[ct];

        // ---- stage 4b: out1 repack through LDS for dense 64B-per-row stores ----
        // lane (q,m) owns rel floats [48ct+12q .. +12) of row m's out1 region.
        // Fencing: sched_barrier(0) = compile-time ordering only (no memory
        // clobber -> VMEM stream keeps flowing); bare lgkmcnt(0) = HW wait for
        // the 6 ds_writes (~64cyc, hideable by co-resident waves). Same-wave
        // DS ops execute in order in the LDS pipe, so this gives cross-lane
        // visibility without a full fence.
        __builtin_amdgcn_sched_barrier(0);
#pragma unroll
        for (int ct = 0; ct < 2; ++ct) {
            float vals[12];
#pragma unroll
            for (int r = 0; r < 4; ++r) {
                const float t = accT[ct][r];
                vals[3*r+0] = fmaf(xy, t, accG0[ct][r]);
                vals[3*r+1] = fmaf(xz, t, accG1[ct][r]);
                vals[3*r+2] = fmaf(xw, t, accG2[ct][r]);
            }
#pragma unroll
            for (int t = 0; t < 3; ++t) {
                const int cs = (48*ct + 12*q + 4*t) ^ swz;   // bijective within [0,96)
                floatx4 piece = {vals[4*t+0], vals[4*t+1], vals[4*t+2], vals[4*t+3]};
                *(floatx4*)(tl + m*96 + cs) = piece;
            }
        }
        __builtin_amdgcn_sched_barrier(0);
        asm volatile("s_waitcnt lgkmcnt(0)");   // bare HW wait, no compiler fence
        __builtin_amdgcn_sched_barrier(0);
        // dense stores: instr p writes rel floats [16p,16p+16) of all 16 rows (1KB/instr)
#pragma unroll
        for (int p = 0; p < 6; ++p) {
            const int cs = (16*p + 4*q) ^ swz;
            const floatx4 piece = *(const floatx4*)(tl + m*96 + cs);
            *(floatx4*)(dst + 64 + 16*p + 4*q) = piece;
        }
    }
}

extern "C" void kernel_launch(void* const* d_in, const int* in_sizes, int n_in,
                              void* d_out, int out_size, void* d_ws, size_t ws_size,
                              hipStream_t stream) {
    const float* x1    = (const float*)d_in[0];
    const float* x2    = (const float*)d_in[1];
    const float* Wss0  = (const float*)d_in[2];
    const float* Wvv0  = (const float*)d_in[3];
    const float* Wsv1  = (const float*)d_in[4];
    const float* Wvs1  = (const float*)d_in[5];
    const float* bias0 = (const float*)d_in[6];
    float* out = (float*)d_out;
    const int n = in_sizes[0] / ROW_IN;   // 400000

    // 768 blocks x 4 waves = 3072 waves -> 3 blocks/CU, 12 waves/CU; ~8
    // tiles/wave amortizes the weight-fragment build.
    dim3 grid(768), block(256);
    hipLaunchKernelGGL(o3tp_kernel, grid, block, 0, stream,
                       x1, x2, Wss0, Wvv0, Wsv1, Wvs1, bias0, out, n);
}